// Round 1
// baseline (507.660 us; speedup 1.0000x reference)
//
#include <hip/hip_runtime.h>
#include <hip/hip_bf16.h>

// ---------------------------------------------------------------------------
// KalmanVAE: B=256, S=512, D=64, L=64, HID=256
// out = [x_recon (131072*64) | z_mean (131072*64) | z_logvar (131072*64)] fp32
//
// Math: z_up_t = M z_{t-1} + c_t,  M = (I-K Hm) A,  c_t = (I-K Hm) z_t + K x_t
//       K = AQ (Hm AQ + R)^-1
// Kernels:
//   kprep : 1 block. AQ, S, S^-1 (Gauss-Jordan, partial pivot), K, G, M;
//           bf16 transposed weight copies for MFMA B-operands.
//   kenc  : encoder GEMMs (bf16 MFMA) + reparam + c_t GEMM. Writes z_mean,
//           z_logvar to out, c (bf16) to ws.
//   kscan : 256 blocks (one per batch), 512 sequential steps, fp32.
//           Writes z_upd fp32 into out region 0 (staging).
//   kdec  : decoder GEMMs (bf16 MFMA), sigmoid, overwrites out region 0.
// ---------------------------------------------------------------------------

typedef short short8 __attribute__((ext_vector_type(8)));
typedef float f32x4 __attribute__((ext_vector_type(4)));

#define NROW 131072      // B*S
#define OUTSEG 8388608   // 131072*64

__device__ __forceinline__ unsigned short f2bf(float f) {
    unsigned int u = __builtin_bit_cast(unsigned int, f);
    u += 0x7fffu + ((u >> 16) & 1u);   // RNE
    return (unsigned short)(u >> 16);
}
__device__ __forceinline__ float bf2f(unsigned short h) {
    unsigned int u = ((unsigned int)h) << 16;
    return __builtin_bit_cast(float, u);
}

// ---------------------------------------------------------------------------
// kprep
// ---------------------------------------------------------------------------
// C = A@B (mode 0) ; C = A@B + Add (mode 1) ; C = I - A@B (mode 2)
__device__ void mm64(const float* A, int lda, const float* B, int ldb,
                     float* C, int ldc, int mode, const float* Add, int ldadd,
                     int tid) {
    int i = tid & 63;
    int j0 = (tid >> 6) * 8;
    float acc[8];
#pragma unroll
    for (int jj = 0; jj < 8; jj++) acc[jj] = 0.f;
    for (int k = 0; k < 64; k++) {
        float a = A[i * lda + k];
#pragma unroll
        for (int jj = 0; jj < 8; jj++) acc[jj] += a * B[k * ldb + j0 + jj];
    }
#pragma unroll
    for (int jj = 0; jj < 8; jj++) {
        int j = j0 + jj;
        float v = acc[jj];
        if (mode == 1) v += Add[i * ldadd + j];
        if (mode == 2) v = ((i == j) ? 1.f : 0.f) - v;
        C[i * ldc + j] = v;
    }
}

__device__ void load64(const float* g, float* L, int tid) {
    for (int idx = tid; idx < 4096; idx += 512)
        L[(idx >> 6) * 65 + (idx & 63)] = g[idx];
}

__global__ __launch_bounds__(512) void kprep(
    const float* __restrict__ Ain, const float* __restrict__ Qin,
    const float* __restrict__ Hin, const float* __restrict__ Rin,
    const float* __restrict__ ew1, const float* __restrict__ ew2,
    const float* __restrict__ dw1, const float* __restrict__ dw2,
    float* __restrict__ Mw, unsigned short* __restrict__ Gb,
    unsigned short* __restrict__ Kb, unsigned short* __restrict__ w1t,
    unsigned short* __restrict__ w2t, unsigned short* __restrict__ d1t,
    unsigned short* __restrict__ d2t) {
    __shared__ float La[64 * 65], Lb[64 * 65], Lc[64 * 65];
    __shared__ float aug[64 * 129];
    __shared__ int pividx;
    __shared__ float pivval;
    int tid = threadIdx.x;

    load64(Ain, La, tid);
    load64(Qin, Lb, tid);
    __syncthreads();
    mm64(La, 65, Lb, 65, Lc, 65, 0, nullptr, 0, tid);  // Lc = AQ
    __syncthreads();
    load64(Hin, La, tid);
    load64(Rin, Lb, tid);
    __syncthreads();
    mm64(La, 65, Lc, 65, aug, 129, 1, Lb, 65, tid);    // aug[:,:64] = Hm@AQ + R
    for (int idx = tid; idx < 4096; idx += 512) {
        int i = idx >> 6, j = idx & 63;
        aug[i * 129 + 64 + j] = (i == j) ? 1.f : 0.f;
    }
    __syncthreads();

    // Gauss-Jordan with partial pivoting -> aug[:,64:128] = S^-1
    for (int k = 0; k < 64; k++) {
        if (tid < 64) {
            float v = (tid >= k) ? fabsf(aug[tid * 129 + k]) : -1.f;
            int ix = tid;
#pragma unroll
            for (int off = 1; off < 64; off <<= 1) {
                float ov = __shfl_xor(v, off);
                int oi = __shfl_xor(ix, off);
                if (ov > v) { v = ov; ix = oi; }
            }
            if (tid == 0) { pividx = ix; pivval = aug[ix * 129 + k]; }
        }
        __syncthreads();
        int p = pividx;
        float rp = 1.0f / pivval;
        if (p != k) {
            if (tid < 128) {
                float t1 = aug[k * 129 + tid];
                aug[k * 129 + tid] = aug[p * 129 + tid];
                aug[p * 129 + tid] = t1;
            }
            __syncthreads();
        }
        // read multipliers (rows i!=k, untouched by scaling) + scale row k
        int i = tid & 63;
        float mlt = (i != k) ? aug[i * 129 + k] : 0.f;
        if (tid < 128) aug[k * 129 + tid] *= rp;
        __syncthreads();
        int j0 = (tid >> 6) * 16;
        if (i != k) {
#pragma unroll
            for (int jj = 0; jj < 16; jj++) {
                int j = j0 + jj;
                aug[i * 129 + j] -= mlt * aug[k * 129 + j];
            }
        }
        __syncthreads();
    }

    mm64(Lc, 65, aug + 64, 129, Lb, 65, 0, nullptr, 0, tid);  // Lb = K
    __syncthreads();
    mm64(Lb, 65, La, 65, Lc, 65, 2, nullptr, 0, tid);         // Lc = I - K@Hm = G
    __syncthreads();
    for (int idx = tid; idx < 4096; idx += 512) {
        int i = idx >> 6, j = idx & 63;
        Kb[idx] = f2bf(Lb[i * 65 + j]);   // K row-major bf16
        Gb[idx] = f2bf(Lc[i * 65 + j]);   // G row-major bf16
    }
    load64(Ain, La, tid);
    __syncthreads();
    mm64(Lc, 65, La, 65, aug, 129, 0, nullptr, 0, tid);       // aug[:,:64] = M = G@A
    __syncthreads();
    for (int idx = tid; idx < 4096; idx += 512)
        Mw[idx] = aug[(idx >> 6) * 129 + (idx & 63)];

    // bf16 transposed weights: Bt[n][k] = W[k][n]
    for (int idx = tid; idx < 256 * 64; idx += 512) {    // w1t[h][d]
        int h = idx >> 6, d = idx & 63;
        w1t[idx] = f2bf(ew1[d * 256 + h]);
    }
    for (int idx = tid; idx < 128 * 256; idx += 512) {   // w2t[o][h]
        int o = idx >> 8, h = idx & 255;
        w2t[idx] = f2bf(ew2[h * 128 + o]);
    }
    for (int idx = tid; idx < 256 * 64; idx += 512) {    // d1t[h][l]
        int h = idx >> 6, l = idx & 63;
        d1t[idx] = f2bf(dw1[l * 256 + h]);
    }
    for (int idx = tid; idx < 64 * 256; idx += 512) {    // d2t[d][h]
        int d = idx >> 8, h = idx & 255;
        d2t[idx] = f2bf(dw2[h * 64 + d]);
    }
}

// ---------------------------------------------------------------------------
// kenc : per block 64 rows. GEMM1 [64,64]@[64,256] relu -> GEMM2 [64,256]@[256,128]
//        -> z_mean/z_logvar/z -> c = z@G^T + x@K^T (bf16 out)
// ---------------------------------------------------------------------------
__global__ __launch_bounds__(256) void kenc(
    const float* __restrict__ x, const float* __restrict__ eps,
    const float* __restrict__ b1, const float* __restrict__ b2,
    const unsigned short* __restrict__ w1t, const unsigned short* __restrict__ w2t,
    const unsigned short* __restrict__ Gb, const unsigned short* __restrict__ Kb,
    unsigned short* __restrict__ cbuf, float* __restrict__ zmean,
    float* __restrict__ zlogv) {
    __shared__ unsigned short Xs[64][72];
    __shared__ unsigned short Hs[64][264];
    __shared__ unsigned short Zs[64][72];
    int row0 = blockIdx.x * 64;
    int tid = threadIdx.x;
    int lane = tid & 63, w = tid >> 6;
    int ml = lane & 15, kg = lane >> 4;

    {   // stage X tile -> bf16 LDS
        int r = tid >> 2, c0 = (tid & 3) * 16;
        const float4* xp = reinterpret_cast<const float4*>(&x[(size_t)(row0 + r) * 64 + c0]);
        float4 v0 = xp[0], v1 = xp[1], v2 = xp[2], v3 = xp[3];
        short8 s0, s1;
        s0[0] = (short)f2bf(v0.x); s0[1] = (short)f2bf(v0.y);
        s0[2] = (short)f2bf(v0.z); s0[3] = (short)f2bf(v0.w);
        s0[4] = (short)f2bf(v1.x); s0[5] = (short)f2bf(v1.y);
        s0[6] = (short)f2bf(v1.z); s0[7] = (short)f2bf(v1.w);
        s1[0] = (short)f2bf(v2.x); s1[1] = (short)f2bf(v2.y);
        s1[2] = (short)f2bf(v2.z); s1[3] = (short)f2bf(v2.w);
        s1[4] = (short)f2bf(v3.x); s1[5] = (short)f2bf(v3.y);
        s1[6] = (short)f2bf(v3.z); s1[7] = (short)f2bf(v3.w);
        *reinterpret_cast<short8*>(&Xs[r][c0]) = s0;
        *reinterpret_cast<short8*>(&Xs[r][c0 + 8]) = s1;
    }
    __syncthreads();

    short8 afr[4][2];
#pragma unroll
    for (int mt = 0; mt < 4; mt++)
#pragma unroll
        for (int kb = 0; kb < 2; kb++)
            afr[mt][kb] = *reinterpret_cast<const short8*>(&Xs[mt * 16 + ml][kb * 32 + kg * 8]);

    // GEMM1: wave w -> n-tiles 4w..4w+3 of H[64,256]
#pragma unroll
    for (int q = 0; q < 4; q++) {
        int nt = w * 4 + q;
        f32x4 acc[4];
#pragma unroll
        for (int mt = 0; mt < 4; mt++) acc[mt] = (f32x4){0.f, 0.f, 0.f, 0.f};
#pragma unroll
        for (int kb = 0; kb < 2; kb++) {
            short8 bfr = *reinterpret_cast<const short8*>(&w1t[(nt * 16 + ml) * 64 + kb * 32 + kg * 8]);
#pragma unroll
            for (int mt = 0; mt < 4; mt++)
                acc[mt] = __builtin_amdgcn_mfma_f32_16x16x32_bf16(afr[mt][kb], bfr, acc[mt], 0, 0, 0);
        }
        float bias = b1[nt * 16 + ml];
#pragma unroll
        for (int mt = 0; mt < 4; mt++)
#pragma unroll
            for (int i = 0; i < 4; i++) {
                float v = acc[mt][i] + bias;
                v = v > 0.f ? v : 0.f;
                Hs[mt * 16 + kg * 4 + i][nt * 16 + ml] = f2bf(v);
            }
    }
    __syncthreads();

    // GEMM2: wave w -> n-tiles {w, w+4} of ML[64,128]  (mean tile + logvar tile)
    f32x4 acc2[2][4];
#pragma unroll
    for (int p = 0; p < 2; p++)
#pragma unroll
        for (int mt = 0; mt < 4; mt++) acc2[p][mt] = (f32x4){0.f, 0.f, 0.f, 0.f};
#pragma unroll
    for (int kb = 0; kb < 8; kb++) {
        short8 a2[4];
#pragma unroll
        for (int mt = 0; mt < 4; mt++)
            a2[mt] = *reinterpret_cast<const short8*>(&Hs[mt * 16 + ml][kb * 32 + kg * 8]);
#pragma unroll
        for (int p = 0; p < 2; p++) {
            int nt = w + 4 * p;
            short8 bfr = *reinterpret_cast<const short8*>(&w2t[(nt * 16 + ml) * 256 + kb * 32 + kg * 8]);
#pragma unroll
            for (int mt = 0; mt < 4; mt++)
                acc2[p][mt] = __builtin_amdgcn_mfma_f32_16x16x32_bf16(a2[mt], bfr, acc2[p][mt], 0, 0, 0);
        }
    }
    int colz = w * 16 + ml;
    float bm = b2[colz], bl = b2[64 + colz];
#pragma unroll
    for (int mt = 0; mt < 4; mt++)
#pragma unroll
        for (int i = 0; i < 4; i++) {
            int r = mt * 16 + kg * 4 + i;
            size_t grow = (size_t)(row0 + r);
            float zm = acc2[0][mt][i] + bm;
            float zl = acc2[1][mt][i] + bl;
            zmean[grow * 64 + colz] = zm;
            zlogv[grow * 64 + colz] = zl;
            float zz = zm + eps[grow * 64 + colz] * expf(0.5f * zl);
            Zs[r][colz] = f2bf(zz);
        }
    __syncthreads();

    // c-GEMM: c = z@G^T + x@K^T ; wave w -> n-tile w
    f32x4 acc3[4];
#pragma unroll
    for (int mt = 0; mt < 4; mt++) acc3[mt] = (f32x4){0.f, 0.f, 0.f, 0.f};
    short8 az[4][2];
#pragma unroll
    for (int mt = 0; mt < 4; mt++)
#pragma unroll
        for (int kb = 0; kb < 2; kb++)
            az[mt][kb] = *reinterpret_cast<const short8*>(&Zs[mt * 16 + ml][kb * 32 + kg * 8]);
#pragma unroll
    for (int kb = 0; kb < 2; kb++) {
        short8 bg = *reinterpret_cast<const short8*>(&Gb[(w * 16 + ml) * 64 + kb * 32 + kg * 8]);
        short8 bk = *reinterpret_cast<const short8*>(&Kb[(w * 16 + ml) * 64 + kb * 32 + kg * 8]);
#pragma unroll
        for (int mt = 0; mt < 4; mt++)
            acc3[mt] = __builtin_amdgcn_mfma_f32_16x16x32_bf16(az[mt][kb], bg, acc3[mt], 0, 0, 0);
#pragma unroll
        for (int mt = 0; mt < 4; mt++)
            acc3[mt] = __builtin_amdgcn_mfma_f32_16x16x32_bf16(afr[mt][kb], bk, acc3[mt], 0, 0, 0);
    }
#pragma unroll
    for (int mt = 0; mt < 4; mt++)
#pragma unroll
        for (int i = 0; i < 4; i++) {
            int r = mt * 16 + kg * 4 + i;
            cbuf[(size_t)(row0 + r) * 64 + colz] = f2bf(acc3[mt][i]);
        }
}

// ---------------------------------------------------------------------------
// kscan : one block per batch. z_t = M z_{t-1} + c_t, 512 steps, fp32.
// thread (j = tid>>2, g = tid&3): partial over k in [16g,16g+16)
// ---------------------------------------------------------------------------
__global__ __launch_bounds__(256) void kscan(const float* __restrict__ Mw,
                                             const unsigned short* __restrict__ cbuf,
                                             float* __restrict__ zu) {
    __shared__ float zs[2][64];
    int b = blockIdx.x, tid = threadIdx.x;
    int j = tid >> 2, g = tid & 3;
    float m[16];
#pragma unroll
    for (int i = 0; i < 16; i++) m[i] = Mw[j * 64 + g * 16 + i];
    if (tid < 128) ((float*)zs)[tid] = 0.f;
    const unsigned short* cb = cbuf + (size_t)b * 512 * 64;
    float* zo = zu + (size_t)b * 512 * 64;
    float cval = bf2f(cb[j]);
    __syncthreads();
    int cur = 0;
    for (int t = 0; t < 512; ++t) {
        unsigned short unext = (t < 511) ? cb[(t + 1) * 64 + j] : (unsigned short)0;
        const float4* zp = reinterpret_cast<const float4*>(&zs[cur][g * 16]);
        float4 z0 = zp[0], z1 = zp[1], z2 = zp[2], z3 = zp[3];
        float pa = m[0] * z0.x + m[1] * z0.y + m[2] * z0.z + m[3] * z0.w;
        float pb = m[4] * z1.x + m[5] * z1.y + m[6] * z1.z + m[7] * z1.w;
        pa += m[8] * z2.x + m[9] * z2.y + m[10] * z2.z + m[11] * z2.w;
        pb += m[12] * z3.x + m[13] * z3.y + m[14] * z3.z + m[15] * z3.w;
        float part = pa + pb;
        part += __shfl_xor(part, 1);
        part += __shfl_xor(part, 2);
        float z = cval + part;
        if (g == 0) {
            zs[cur ^ 1][j] = z;
            zo[(size_t)t * 64 + j] = z;
        }
        cval = bf2f(unext);
        cur ^= 1;
        __syncthreads();
    }
}

// ---------------------------------------------------------------------------
// kdec : in-place over out region 0: reads z_upd fp32, writes x_recon fp32.
// ---------------------------------------------------------------------------
__global__ __launch_bounds__(256) void kdec(float* __restrict__ xr,
                                            const float* __restrict__ db1,
                                            const float* __restrict__ db2,
                                            const unsigned short* __restrict__ d1t,
                                            const unsigned short* __restrict__ d2t) {
    __shared__ unsigned short Zs[64][72];
    __shared__ unsigned short Hs[64][264];
    int row0 = blockIdx.x * 64;
    int tid = threadIdx.x;
    int lane = tid & 63, w = tid >> 6;
    int ml = lane & 15, kg = lane >> 4;

    {
        int r = tid >> 2, c0 = (tid & 3) * 16;
        const float4* zp = reinterpret_cast<const float4*>(&xr[(size_t)(row0 + r) * 64 + c0]);
        float4 v0 = zp[0], v1 = zp[1], v2 = zp[2], v3 = zp[3];
        short8 s0, s1;
        s0[0] = (short)f2bf(v0.x); s0[1] = (short)f2bf(v0.y);
        s0[2] = (short)f2bf(v0.z); s0[3] = (short)f2bf(v0.w);
        s0[4] = (short)f2bf(v1.x); s0[5] = (short)f2bf(v1.y);
        s0[6] = (short)f2bf(v1.z); s0[7] = (short)f2bf(v1.w);
        s1[0] = (short)f2bf(v2.x); s1[1] = (short)f2bf(v2.y);
        s1[2] = (short)f2bf(v2.z); s1[3] = (short)f2bf(v2.w);
        s1[4] = (short)f2bf(v3.x); s1[5] = (short)f2bf(v3.y);
        s1[6] = (short)f2bf(v3.z); s1[7] = (short)f2bf(v3.w);
        *reinterpret_cast<short8*>(&Zs[r][c0]) = s0;
        *reinterpret_cast<short8*>(&Zs[r][c0 + 8]) = s1;
    }
    __syncthreads();

    short8 afr[4][2];
#pragma unroll
    for (int mt = 0; mt < 4; mt++)
#pragma unroll
        for (int kb = 0; kb < 2; kb++)
            afr[mt][kb] = *reinterpret_cast<const short8*>(&Zs[mt * 16 + ml][kb * 32 + kg * 8]);

#pragma unroll
    for (int q = 0; q < 4; q++) {
        int nt = w * 4 + q;
        f32x4 acc[4];
#pragma unroll
        for (int mt = 0; mt < 4; mt++) acc[mt] = (f32x4){0.f, 0.f, 0.f, 0.f};
#pragma unroll
        for (int kb = 0; kb < 2; kb++) {
            short8 bfr = *reinterpret_cast<const short8*>(&d1t[(nt * 16 + ml) * 64 + kb * 32 + kg * 8]);
#pragma unroll
            for (int mt = 0; mt < 4; mt++)
                acc[mt] = __builtin_amdgcn_mfma_f32_16x16x32_bf16(afr[mt][kb], bfr, acc[mt], 0, 0, 0);
        }
        float bias = db1[nt * 16 + ml];
#pragma unroll
        for (int mt = 0; mt < 4; mt++)
#pragma unroll
            for (int i = 0; i < 4; i++) {
                float v = acc[mt][i] + bias;
                v = v > 0.f ? v : 0.f;
                Hs[mt * 16 + kg * 4 + i][nt * 16 + ml] = f2bf(v);
            }
    }
    __syncthreads();

    f32x4 acc2[4];
#pragma unroll
    for (int mt = 0; mt < 4; mt++) acc2[mt] = (f32x4){0.f, 0.f, 0.f, 0.f};
#pragma unroll
    for (int kb = 0; kb < 8; kb++) {
        short8 bfr = *reinterpret_cast<const short8*>(&d2t[(w * 16 + ml) * 256 + kb * 32 + kg * 8]);
#pragma unroll
        for (int mt = 0; mt < 4; mt++) {
            short8 a2 = *reinterpret_cast<const short8*>(&Hs[mt * 16 + ml][kb * 32 + kg * 8]);
            acc2[mt] = __builtin_amdgcn_mfma_f32_16x16x32_bf16(a2, bfr, acc2[mt], 0, 0, 0);
        }
    }
    float bias2 = db2[w * 16 + ml];
#pragma unroll
    for (int mt = 0; mt < 4; mt++)
#pragma unroll
        for (int i = 0; i < 4; i++) {
            int r = mt * 16 + kg * 4 + i;
            float v = acc2[mt][i] + bias2;
            float s = 1.f / (1.f + expf(-v));
            xr[(size_t)(row0 + r) * 64 + w * 16 + ml] = s;
        }
}

// ---------------------------------------------------------------------------
extern "C" void kernel_launch(void* const* d_in, const int* in_sizes, int n_in,
                              void* d_out, int out_size, void* d_ws, size_t ws_size,
                              hipStream_t stream) {
    (void)in_sizes; (void)n_in; (void)out_size; (void)ws_size;
    const float* x      = (const float*)d_in[0];
    const float* eps    = (const float*)d_in[1];
    const float* enc_w1 = (const float*)d_in[2];
    const float* enc_b1 = (const float*)d_in[3];
    const float* enc_w2 = (const float*)d_in[4];
    const float* enc_b2 = (const float*)d_in[5];
    const float* dec_w1 = (const float*)d_in[6];
    const float* dec_b1 = (const float*)d_in[7];
    const float* dec_w2 = (const float*)d_in[8];
    const float* dec_b2 = (const float*)d_in[9];
    const float* Ain    = (const float*)d_in[10];
    const float* Qin    = (const float*)d_in[11];
    const float* Hin    = (const float*)d_in[12];
    const float* Rin    = (const float*)d_in[13];

    float* out   = (float*)d_out;
    float* xrec  = out;               // also z_upd staging
    float* zmean = out + OUTSEG;
    float* zlogv = out + 2 * OUTSEG;

    char* ws = (char*)d_ws;
    float*          Mw   = (float*)(ws);                 // 16384 B
    unsigned short* Gb   = (unsigned short*)(ws + 16384);
    unsigned short* Kb   = (unsigned short*)(ws + 24576);
    unsigned short* w1t  = (unsigned short*)(ws + 32768);
    unsigned short* w2t  = (unsigned short*)(ws + 65536);
    unsigned short* d1t  = (unsigned short*)(ws + 131072);
    unsigned short* d2t  = (unsigned short*)(ws + 163840);
    unsigned short* cbuf = (unsigned short*)(ws + 196608);  // 16.0 MiB

    hipLaunchKernelGGL(kprep, dim3(1), dim3(512), 0, stream,
                       Ain, Qin, Hin, Rin, enc_w1, enc_w2, dec_w1, dec_w2,
                       Mw, Gb, Kb, w1t, w2t, d1t, d2t);
    hipLaunchKernelGGL(kenc, dim3(2048), dim3(256), 0, stream,
                       x, eps, enc_b1, enc_b2, w1t, w2t, Gb, Kb, cbuf, zmean, zlogv);
    hipLaunchKernelGGL(kscan, dim3(256), dim3(256), 0, stream, Mw, cbuf, xrec);
    hipLaunchKernelGGL(kdec, dim3(2048), dim3(256), 0, stream,
                       xrec, dec_b1, dec_b2, d1t, d2t);
}

// Round 2
// 424.197 us; speedup vs baseline: 1.1968x; 1.1968x over previous
//
#include <hip/hip_runtime.h>
#include <hip/hip_bf16.h>

// ---------------------------------------------------------------------------
// KalmanVAE: B=256, S=512, D=64, L=64, HID=256
// out = [x_recon | z_mean | z_logvar], each 131072*64 fp32
//
// z_up_t = M z_{t-1} + c_t,  M = (I-K Hm) A,  c_t = (I-K Hm) z_t + K x_t
// Chunked scan: 32 chunks of 16 steps per batch.
//   kenc  : encoder GEMMs + c-GEMM + phase-A local chunk scans -> Pbuf[c+1]=f[c]
//   kchain: per-batch chunk prefix  P[c] = f[c-1] + M^16 P[c-1]  (in-place)
//   kdec  : phase-C chunk scans (correct init) -> decoder GEMMs -> x_recon
// ---------------------------------------------------------------------------

typedef short short8 __attribute__((ext_vector_type(8)));
typedef float f32x4 __attribute__((ext_vector_type(4)));

#define OUTSEG 8388608   // 131072*64

__device__ __forceinline__ unsigned short f2bf(float f) {
    unsigned int u = __builtin_bit_cast(unsigned int, f);
    u += 0x7fffu + ((u >> 16) & 1u);   // RNE
    return (unsigned short)(u >> 16);
}
__device__ __forceinline__ float bf2f(unsigned short h) {
    unsigned int u = ((unsigned int)h) << 16;
    return __builtin_bit_cast(float, u);
}
__device__ __forceinline__ float rlf(float v, int l) {
    return __builtin_bit_cast(float, __builtin_amdgcn_readlane(__builtin_bit_cast(int, v), l));
}
// z_new[j] = c[j] + sum_k m[k] * z[k]   (m = row j of M, one wave, no barriers)
__device__ __forceinline__ float matvec_rl(const float* m, float z, float c) {
    float a0 = c, a1 = 0.f, a2 = 0.f, a3 = 0.f;
#pragma unroll
    for (int k = 0; k < 64; k += 4) {
        a0 = fmaf(m[k + 0], rlf(z, k + 0), a0);
        a1 = fmaf(m[k + 1], rlf(z, k + 1), a1);
        a2 = fmaf(m[k + 2], rlf(z, k + 2), a2);
        a3 = fmaf(m[k + 3], rlf(z, k + 3), a3);
    }
    return (a0 + a1) + (a2 + a3);
}
__device__ __forceinline__ void load_mrow(const float* Mp, int j, float* m) {
#pragma unroll
    for (int q = 0; q < 16; q++) {
        float4 v = *reinterpret_cast<const float4*>(&Mp[j * 64 + q * 4]);
        m[q * 4 + 0] = v.x; m[q * 4 + 1] = v.y;
        m[q * 4 + 2] = v.z; m[q * 4 + 3] = v.w;
    }
}

// ---------------------------------------------------------------------------
// kprep: block 0 = matrix chain (256 thr); blocks 1..20 = weight transposes
// ---------------------------------------------------------------------------
// C = A@B (0) ; C = A@B + Add (1) ; C = I - A@B (2)   [256 threads]
__device__ void mm64(const float* A, int lda, const float* B, int ldb,
                     float* C, int ldc, int mode, const float* Add, int ldadd,
                     int tid) {
    int i = tid & 63;
    int j0 = (tid >> 6) * 16;
    float acc[16];
#pragma unroll
    for (int jj = 0; jj < 16; jj++) acc[jj] = 0.f;
    for (int k = 0; k < 64; k++) {
        float a = A[i * lda + k];
#pragma unroll
        for (int jj = 0; jj < 16; jj++) acc[jj] += a * B[k * ldb + j0 + jj];
    }
#pragma unroll
    for (int jj = 0; jj < 16; jj++) {
        int j = j0 + jj;
        float v = acc[jj];
        if (mode == 1) v += Add[i * ldadd + j];
        if (mode == 2) v = ((i == j) ? 1.f : 0.f) - v;
        C[i * ldc + j] = v;
    }
}

__device__ void load64(const float* g, float* L, int tid) {
    for (int idx = tid; idx < 4096; idx += 256)
        L[(idx >> 6) * 65 + (idx & 63)] = g[idx];
}

__device__ void tr_tile(const float* src, int sld, unsigned short* dst, int dld,
                        int r0, int c0, int tid, float* LT) {
    int rr = tid >> 2, q = tid & 3;
#pragma unroll
    for (int u = 0; u < 4; u++) {
        float4 v = *reinterpret_cast<const float4*>(
            &src[(size_t)(r0 + rr) * sld + c0 + q * 16 + u * 4]);
        LT[rr * 65 + q * 16 + u * 4 + 0] = v.x;
        LT[rr * 65 + q * 16 + u * 4 + 1] = v.y;
        LT[rr * 65 + q * 16 + u * 4 + 2] = v.z;
        LT[rr * 65 + q * 16 + u * 4 + 3] = v.w;
    }
    __syncthreads();
    short8 s0, s1;
#pragma unroll
    for (int u = 0; u < 8; u++) s0[u] = (short)f2bf(LT[(q * 16 + u) * 65 + rr]);
#pragma unroll
    for (int u = 0; u < 8; u++) s1[u] = (short)f2bf(LT[(q * 16 + 8 + u) * 65 + rr]);
    *reinterpret_cast<short8*>(&dst[(size_t)(c0 + rr) * dld + r0 + q * 16]) = s0;
    *reinterpret_cast<short8*>(&dst[(size_t)(c0 + rr) * dld + r0 + q * 16 + 8]) = s1;
}

__global__ __launch_bounds__(256) void kprep(
    const float* __restrict__ Ain, const float* __restrict__ Qin,
    const float* __restrict__ Hin, const float* __restrict__ Rin,
    const float* __restrict__ ew1, const float* __restrict__ ew2,
    const float* __restrict__ dw1, const float* __restrict__ dw2,
    float* __restrict__ Mw, float* __restrict__ M16w,
    unsigned short* __restrict__ Gb, unsigned short* __restrict__ Kb,
    unsigned short* __restrict__ w1t, unsigned short* __restrict__ w2t,
    unsigned short* __restrict__ d1t, unsigned short* __restrict__ d2t) {
    __shared__ float La[64 * 65], Lb[64 * 65], Lc[64 * 65];
    __shared__ float aug[64 * 129];
    __shared__ int s_piv;
    __shared__ float s_pv;
    int tid = threadIdx.x;

    if (blockIdx.x != 0) {
        int t = blockIdx.x - 1;
        const float* src; unsigned short* dst; int sld, dld, r0, c0;
        if (t < 4)       { src = ew1; dst = w1t; sld = 256; dld = 64;  r0 = 0;             c0 = t * 64; }
        else if (t < 12) { int i = t - 4;  src = ew2; dst = w2t; sld = 128; dld = 256; r0 = (i >> 1) * 64; c0 = (i & 1) * 64; }
        else if (t < 16) { int i = t - 12; src = dw1; dst = d1t; sld = 256; dld = 64;  r0 = 0;             c0 = i * 64; }
        else             { int i = t - 16; src = dw2; dst = d2t; sld = 64;  dld = 256; r0 = i * 64;        c0 = 0; }
        tr_tile(src, sld, dst, dld, r0, c0, tid, La);
        return;
    }

    // ---- block 0: matrix chain ----
    load64(Ain, La, tid);
    load64(Qin, Lb, tid);
    __syncthreads();
    mm64(La, 65, Lb, 65, Lc, 65, 0, nullptr, 0, tid);          // Lc = AQ
    __syncthreads();
    load64(Hin, La, tid);
    load64(Rin, Lb, tid);
    __syncthreads();
    mm64(La, 65, Lc, 65, aug, 129, 1, Lb, 65, tid);            // aug[:, :64] = Hm@AQ + R
    for (int idx = tid; idx < 4096; idx += 256) {
        int i = idx >> 6, j = idx & 63;
        aug[i * 129 + 64 + j] = (i == j) ? 1.f : 0.f;
    }
    __syncthreads();

    // Gauss-Jordan with partial pivoting -> aug[:,64:128] = S^-1
    for (int k = 0; k < 64; k++) {
        if (tid < 64) {
            float v = (tid >= k) ? fabsf(aug[tid * 129 + k]) : -1.f;
            int ix = tid;
#pragma unroll
            for (int off = 1; off < 64; off <<= 1) {
                float ov = __shfl_xor(v, off);
                int oi = __shfl_xor(ix, off);
                if (ov > v) { v = ov; ix = oi; }
            }
            if (tid == 0) { s_piv = ix; s_pv = aug[ix * 129 + k]; }
        }
        __syncthreads();
        int p = s_piv;
        float rp = 1.0f / s_pv;
        if (p != k) {
            for (int idx = tid; idx < 129; idx += 256) {
                float t1 = aug[k * 129 + idx];
                aug[k * 129 + idx] = aug[p * 129 + idx];
                aug[p * 129 + idx] = t1;
            }
            __syncthreads();
        }
        int i = tid & 63, jb = tid >> 6;
        float mlt = aug[i * 129 + k] * rp;
        float pv[33], rw[33];
#pragma unroll
        for (int jj = 0; jj < 33; jj++) {
            int j = jb + 4 * jj;
            if (j < 129) { pv[jj] = aug[k * 129 + j]; rw[jj] = aug[i * 129 + j]; }
        }
        __syncthreads();
#pragma unroll
        for (int jj = 0; jj < 33; jj++) {
            int j = jb + 4 * jj;
            if (j < 129) aug[i * 129 + j] = (i == k) ? pv[jj] * rp : rw[jj] - mlt * pv[jj];
        }
        __syncthreads();
    }

    mm64(Lc, 65, aug + 64, 129, Lb, 65, 0, nullptr, 0, tid);   // Lb = K
    __syncthreads();
    mm64(Lb, 65, La, 65, Lc, 65, 2, nullptr, 0, tid);          // Lc = I - K@Hm = G
    __syncthreads();
    for (int idx = tid; idx < 4096; idx += 256) {
        int i = idx >> 6, j = idx & 63;
        Kb[idx] = f2bf(Lb[i * 65 + j]);
        Gb[idx] = f2bf(Lc[i * 65 + j]);
    }
    load64(Ain, La, tid);
    __syncthreads();
    mm64(Lc, 65, La, 65, aug, 129, 0, nullptr, 0, tid);        // aug = M = G@A
    __syncthreads();
    for (int idx = tid; idx < 4096; idx += 256)
        Mw[idx] = aug[(idx >> 6) * 129 + (idx & 63)];
    __syncthreads();
    mm64(aug, 129, aug, 129, Lb, 65, 0, nullptr, 0, tid);      // Lb = M^2
    __syncthreads();
    mm64(Lb, 65, Lb, 65, Lc, 65, 0, nullptr, 0, tid);          // Lc = M^4
    __syncthreads();
    mm64(Lc, 65, Lc, 65, La, 65, 0, nullptr, 0, tid);          // La = M^8
    __syncthreads();
    mm64(La, 65, La, 65, Lb, 65, 0, nullptr, 0, tid);          // Lb = M^16
    __syncthreads();
    for (int idx = tid; idx < 4096; idx += 256)
        M16w[idx] = Lb[(idx >> 6) * 65 + (idx & 63)];
}

// ---------------------------------------------------------------------------
// kenc : 64 rows/block. GEMM1 -> relu -> GEMM2 -> reparam -> c-GEMM ->
//        coalesced cbuf store + phase-A chunk scans (4 waves x 16 steps).
// ---------------------------------------------------------------------------
__global__ __launch_bounds__(256) void kenc(
    const float* __restrict__ x, const float* __restrict__ eps,
    const float* __restrict__ b1, const float* __restrict__ b2,
    const unsigned short* __restrict__ w1t, const unsigned short* __restrict__ w2t,
    const unsigned short* __restrict__ Gb, const unsigned short* __restrict__ Kb,
    const float* __restrict__ Mw, unsigned short* __restrict__ cbuf,
    float* __restrict__ Pbuf, float* __restrict__ zmean,
    float* __restrict__ zlogv) {
    __shared__ unsigned short Xs[64][72];   // x tile, later reused as c tile
    __shared__ unsigned short Hs[64][264];
    __shared__ unsigned short Zs[64][72];
    int row0 = blockIdx.x * 64;
    int tid = threadIdx.x;
    int lane = tid & 63, w = tid >> 6;
    int ml = lane & 15, kg = lane >> 4;

    {   // stage X tile -> bf16 LDS
        int r = tid >> 2, c0 = (tid & 3) * 16;
        const float4* xp = reinterpret_cast<const float4*>(&x[(size_t)(row0 + r) * 64 + c0]);
        float4 v0 = xp[0], v1 = xp[1], v2 = xp[2], v3 = xp[3];
        short8 s0, s1;
        s0[0] = (short)f2bf(v0.x); s0[1] = (short)f2bf(v0.y);
        s0[2] = (short)f2bf(v0.z); s0[3] = (short)f2bf(v0.w);
        s0[4] = (short)f2bf(v1.x); s0[5] = (short)f2bf(v1.y);
        s0[6] = (short)f2bf(v1.z); s0[7] = (short)f2bf(v1.w);
        s1[0] = (short)f2bf(v2.x); s1[1] = (short)f2bf(v2.y);
        s1[2] = (short)f2bf(v2.z); s1[3] = (short)f2bf(v2.w);
        s1[4] = (short)f2bf(v3.x); s1[5] = (short)f2bf(v3.y);
        s1[6] = (short)f2bf(v3.z); s1[7] = (short)f2bf(v3.w);
        *reinterpret_cast<short8*>(&Xs[r][c0]) = s0;
        *reinterpret_cast<short8*>(&Xs[r][c0 + 8]) = s1;
    }
    __syncthreads();

    short8 afr[4][2];
#pragma unroll
    for (int mt = 0; mt < 4; mt++)
#pragma unroll
        for (int kb = 0; kb < 2; kb++)
            afr[mt][kb] = *reinterpret_cast<const short8*>(&Xs[mt * 16 + ml][kb * 32 + kg * 8]);

    // GEMM1: wave w -> n-tiles 4w..4w+3 of H[64,256]
#pragma unroll
    for (int q = 0; q < 4; q++) {
        int nt = w * 4 + q;
        f32x4 acc[4];
#pragma unroll
        for (int mt = 0; mt < 4; mt++) acc[mt] = (f32x4){0.f, 0.f, 0.f, 0.f};
#pragma unroll
        for (int kb = 0; kb < 2; kb++) {
            short8 bfr = *reinterpret_cast<const short8*>(&w1t[(nt * 16 + ml) * 64 + kb * 32 + kg * 8]);
#pragma unroll
            for (int mt = 0; mt < 4; mt++)
                acc[mt] = __builtin_amdgcn_mfma_f32_16x16x32_bf16(afr[mt][kb], bfr, acc[mt], 0, 0, 0);
        }
        float bias = b1[nt * 16 + ml];
#pragma unroll
        for (int mt = 0; mt < 4; mt++)
#pragma unroll
            for (int i = 0; i < 4; i++) {
                float v = acc[mt][i] + bias;
                v = v > 0.f ? v : 0.f;
                Hs[mt * 16 + kg * 4 + i][nt * 16 + ml] = f2bf(v);
            }
    }
    __syncthreads();

    // GEMM2: wave w -> n-tiles {w, w+4} of ML[64,128]
    f32x4 acc2[2][4];
#pragma unroll
    for (int p = 0; p < 2; p++)
#pragma unroll
        for (int mt = 0; mt < 4; mt++) acc2[p][mt] = (f32x4){0.f, 0.f, 0.f, 0.f};
#pragma unroll
    for (int kb = 0; kb < 8; kb++) {
        short8 a2[4];
#pragma unroll
        for (int mt = 0; mt < 4; mt++)
            a2[mt] = *reinterpret_cast<const short8*>(&Hs[mt * 16 + ml][kb * 32 + kg * 8]);
#pragma unroll
        for (int p = 0; p < 2; p++) {
            int nt = w + 4 * p;
            short8 bfr = *reinterpret_cast<const short8*>(&w2t[(nt * 16 + ml) * 256 + kb * 32 + kg * 8]);
#pragma unroll
            for (int mt = 0; mt < 4; mt++)
                acc2[p][mt] = __builtin_amdgcn_mfma_f32_16x16x32_bf16(a2[mt], bfr, acc2[p][mt], 0, 0, 0);
        }
    }
    int colz = w * 16 + ml;
    float bm = b2[colz], bl = b2[64 + colz];
#pragma unroll
    for (int mt = 0; mt < 4; mt++)
#pragma unroll
        for (int i = 0; i < 4; i++) {
            int r = mt * 16 + kg * 4 + i;
            size_t grow = (size_t)(row0 + r);
            float zm = acc2[0][mt][i] + bm;
            float zl = acc2[1][mt][i] + bl;
            zmean[grow * 64 + colz] = zm;
            zlogv[grow * 64 + colz] = zl;
            float zz = zm + eps[grow * 64 + colz] * expf(0.5f * zl);
            Zs[r][colz] = f2bf(zz);
        }
    __syncthreads();

    // c-GEMM: c = z@G^T + x@K^T ; wave w -> n-tile w
    f32x4 acc3[4];
#pragma unroll
    for (int mt = 0; mt < 4; mt++) acc3[mt] = (f32x4){0.f, 0.f, 0.f, 0.f};
    short8 az[4][2];
#pragma unroll
    for (int mt = 0; mt < 4; mt++)
#pragma unroll
        for (int kb = 0; kb < 2; kb++)
            az[mt][kb] = *reinterpret_cast<const short8*>(&Zs[mt * 16 + ml][kb * 32 + kg * 8]);
#pragma unroll
    for (int kb = 0; kb < 2; kb++) {
        short8 bg = *reinterpret_cast<const short8*>(&Gb[(w * 16 + ml) * 64 + kb * 32 + kg * 8]);
        short8 bk = *reinterpret_cast<const short8*>(&Kb[(w * 16 + ml) * 64 + kb * 32 + kg * 8]);
#pragma unroll
        for (int mt = 0; mt < 4; mt++)
            acc3[mt] = __builtin_amdgcn_mfma_f32_16x16x32_bf16(az[mt][kb], bg, acc3[mt], 0, 0, 0);
#pragma unroll
        for (int mt = 0; mt < 4; mt++)
            acc3[mt] = __builtin_amdgcn_mfma_f32_16x16x32_bf16(afr[mt][kb], bk, acc3[mt], 0, 0, 0);
    }
    // stage c into Xs (x-tile dead: afr lives in regs)
#pragma unroll
    for (int mt = 0; mt < 4; mt++)
#pragma unroll
        for (int i = 0; i < 4; i++)
            Xs[mt * 16 + kg * 4 + i][colz] = f2bf(acc3[mt][i]);
    __syncthreads();

    {   // coalesced cbuf store
        int r = tid >> 2, c0 = (tid & 3) * 16;
        short8 s0 = *reinterpret_cast<const short8*>(&Xs[r][c0]);
        short8 s1 = *reinterpret_cast<const short8*>(&Xs[r][c0 + 8]);
        *reinterpret_cast<short8*>(&cbuf[(size_t)(row0 + r) * 64 + c0]) = s0;
        *reinterpret_cast<short8*>(&cbuf[(size_t)(row0 + r) * 64 + c0 + 8]) = s1;
    }

    {   // phase-A local scan: wave w scans chunk rows [16w, 16w+16), zero init
        int j = lane;
        float m[64];
        load_mrow(Mw, j, m);
        unsigned short cv[16];
#pragma unroll
        for (int t = 0; t < 16; t++) cv[t] = Xs[w * 16 + t][j];
        float z = bf2f(cv[0]);
#pragma unroll
        for (int t = 1; t < 16; t++) z = matvec_rl(m, z, bf2f(cv[t]));
        int b = row0 >> 9;
        int chunk = ((row0 & 511) >> 4) + w;        // 0..31
        if (chunk != 31)                            // f[chunk] -> Pbuf slot chunk+1
            Pbuf[((size_t)b * 32 + chunk + 1) * 64 + j] = z;
    }
}

// ---------------------------------------------------------------------------
// kchain : per batch, P[0]=0 ; P[c] = f[c-1] + M16 P[c-1]  (in-place on Pbuf)
// ---------------------------------------------------------------------------
__global__ __launch_bounds__(64) void kchain(const float* __restrict__ M16w,
                                             float* __restrict__ Pbuf) {
    int b = blockIdx.x, j = threadIdx.x;
    float m[64];
    load_mrow(M16w, j, m);
    float* P = Pbuf + (size_t)b * 32 * 64;
    P[j] = 0.f;                                     // P[0]
    float z = 0.f;
    for (int c = 1; c < 32; c++) {
        float f = P[c * 64 + j];                    // holds f[c-1]
        z = matvec_rl(m, z, f);
        P[c * 64 + j] = z;
    }
}

// ---------------------------------------------------------------------------
// kdec : phase-C chunk scans (4 waves x 16 steps) -> Zs bf16 -> decoder GEMMs
// ---------------------------------------------------------------------------
__global__ __launch_bounds__(256) void kdec(float* __restrict__ xr,
                                            const float* __restrict__ db1,
                                            const float* __restrict__ db2,
                                            const unsigned short* __restrict__ d1t,
                                            const unsigned short* __restrict__ d2t,
                                            const float* __restrict__ Mw,
                                            const float* __restrict__ Pbuf,
                                            const unsigned short* __restrict__ cbuf) {
    __shared__ unsigned short Zs[64][72];
    __shared__ unsigned short Hs[64][264];
    int row0 = blockIdx.x * 64;
    int tid = threadIdx.x;
    int lane = tid & 63, w = tid >> 6;
    int ml = lane & 15, kg = lane >> 4;

    {   // phase-C scan: wave w -> chunk rows [16w,16w+16) with correct init
        int j = lane;
        int b = row0 >> 9;
        int chunk = ((row0 & 511) >> 4) + w;
        float m[64];
        load_mrow(Mw, j, m);
        float z = Pbuf[((size_t)b * 32 + chunk) * 64 + j];
        const unsigned short* cb = cbuf + ((size_t)row0 + w * 16) * 64;
        unsigned short cv[16];
#pragma unroll
        for (int t = 0; t < 16; t++) cv[t] = cb[t * 64 + j];
#pragma unroll
        for (int t = 0; t < 16; t++) {
            z = matvec_rl(m, z, bf2f(cv[t]));
            Zs[w * 16 + t][j] = f2bf(z);
        }
    }
    __syncthreads();

    short8 afr[4][2];
#pragma unroll
    for (int mt = 0; mt < 4; mt++)
#pragma unroll
        for (int kb = 0; kb < 2; kb++)
            afr[mt][kb] = *reinterpret_cast<const short8*>(&Zs[mt * 16 + ml][kb * 32 + kg * 8]);

#pragma unroll
    for (int q = 0; q < 4; q++) {
        int nt = w * 4 + q;
        f32x4 acc[4];
#pragma unroll
        for (int mt = 0; mt < 4; mt++) acc[mt] = (f32x4){0.f, 0.f, 0.f, 0.f};
#pragma unroll
        for (int kb = 0; kb < 2; kb++) {
            short8 bfr = *reinterpret_cast<const short8*>(&d1t[(nt * 16 + ml) * 64 + kb * 32 + kg * 8]);
#pragma unroll
            for (int mt = 0; mt < 4; mt++)
                acc[mt] = __builtin_amdgcn_mfma_f32_16x16x32_bf16(afr[mt][kb], bfr, acc[mt], 0, 0, 0);
        }
        float bias = db1[nt * 16 + ml];
#pragma unroll
        for (int mt = 0; mt < 4; mt++)
#pragma unroll
            for (int i = 0; i < 4; i++) {
                float v = acc[mt][i] + bias;
                v = v > 0.f ? v : 0.f;
                Hs[mt * 16 + kg * 4 + i][nt * 16 + ml] = f2bf(v);
            }
    }
    __syncthreads();

    f32x4 acc2[4];
#pragma unroll
    for (int mt = 0; mt < 4; mt++) acc2[mt] = (f32x4){0.f, 0.f, 0.f, 0.f};
#pragma unroll
    for (int kb = 0; kb < 8; kb++) {
        short8 bfr = *reinterpret_cast<const short8*>(&d2t[(w * 16 + ml) * 256 + kb * 32 + kg * 8]);
#pragma unroll
        for (int mt = 0; mt < 4; mt++) {
            short8 a2 = *reinterpret_cast<const short8*>(&Hs[mt * 16 + ml][kb * 32 + kg * 8]);
            acc2[mt] = __builtin_amdgcn_mfma_f32_16x16x32_bf16(a2, bfr, acc2[mt], 0, 0, 0);
        }
    }
    float bias2 = db2[w * 16 + ml];
#pragma unroll
    for (int mt = 0; mt < 4; mt++)
#pragma unroll
        for (int i = 0; i < 4; i++) {
            int r = mt * 16 + kg * 4 + i;
            float v = acc2[mt][i] + bias2;
            float s = 1.f / (1.f + expf(-v));
            xr[(size_t)(row0 + r) * 64 + w * 16 + ml] = s;
        }
}

// ---------------------------------------------------------------------------
extern "C" void kernel_launch(void* const* d_in, const int* in_sizes, int n_in,
                              void* d_out, int out_size, void* d_ws, size_t ws_size,
                              hipStream_t stream) {
    (void)in_sizes; (void)n_in; (void)out_size; (void)ws_size;
    const float* x      = (const float*)d_in[0];
    const float* eps    = (const float*)d_in[1];
    const float* enc_w1 = (const float*)d_in[2];
    const float* enc_b1 = (const float*)d_in[3];
    const float* enc_w2 = (const float*)d_in[4];
    const float* enc_b2 = (const float*)d_in[5];
    const float* dec_w1 = (const float*)d_in[6];
    const float* dec_b1 = (const float*)d_in[7];
    const float* dec_w2 = (const float*)d_in[8];
    const float* dec_b2 = (const float*)d_in[9];
    const float* Ain    = (const float*)d_in[10];
    const float* Qin    = (const float*)d_in[11];
    const float* Hin    = (const float*)d_in[12];
    const float* Rin    = (const float*)d_in[13];

    float* out   = (float*)d_out;
    float* xrec  = out;
    float* zmean = out + OUTSEG;
    float* zlogv = out + 2 * OUTSEG;

    char* ws = (char*)d_ws;
    float*          Mw   = (float*)(ws);                   // 16 KB
    float*          M16w = (float*)(ws + 16384);           // 16 KB
    unsigned short* Gb   = (unsigned short*)(ws + 32768);  // 8 KB
    unsigned short* Kb   = (unsigned short*)(ws + 40960);  // 8 KB
    unsigned short* w1t  = (unsigned short*)(ws + 49152);  // 32 KB
    unsigned short* w2t  = (unsigned short*)(ws + 81920);  // 64 KB
    unsigned short* d1t  = (unsigned short*)(ws + 147456); // 32 KB
    unsigned short* d2t  = (unsigned short*)(ws + 180224); // 32 KB
    float*          Pbuf = (float*)(ws + 212992);          // 2 MB
    unsigned short* cbuf = (unsigned short*)(ws + 2310144);// 16 MB  (end 18.2MB)

    hipLaunchKernelGGL(kprep, dim3(21), dim3(256), 0, stream,
                       Ain, Qin, Hin, Rin, enc_w1, enc_w2, dec_w1, dec_w2,
                       Mw, M16w, Gb, Kb, w1t, w2t, d1t, d2t);
    hipLaunchKernelGGL(kenc, dim3(2048), dim3(256), 0, stream,
                       x, eps, enc_b1, enc_b2, w1t, w2t, Gb, Kb, Mw, cbuf, Pbuf,
                       zmean, zlogv);
    hipLaunchKernelGGL(kchain, dim3(256), dim3(64), 0, stream, M16w, Pbuf);
    hipLaunchKernelGGL(kdec, dim3(2048), dim3(256), 0, stream,
                       xrec, dec_b1, dec_b2, d1t, d2t, Mw, Pbuf, cbuf);
}